// Round 13
// baseline (7744.587 us; speedup 1.0000x reference)
//
#include <hip/hip_runtime.h>
#include <hip/hip_bf16.h>
#include <cstddef>

typedef __attribute__((ext_vector_type(8))) short bf16x8;
typedef __attribute__((ext_vector_type(4))) float f32x4;
typedef __attribute__((ext_vector_type(4))) unsigned int u32x4;

constexpr int kB = 64;      // batch
constexpr int kS = 1024;    // seq len
constexpr int kH = 512;     // hidden (== input size)
constexpr int kNBG = 4;     // batch groups (16 batches each)
constexpr int kNUG = 32;    // unit groups per layer (16 units each)
constexpr int kHst = 520;   // padded LDS h-stage row stride (elems)
constexpr unsigned kDone4 = 0x01010101u;
constexpr int kSpinCap = 1 << 16;  // fail-fast

__device__ __forceinline__ unsigned short f2bf(float f) {
  unsigned int u = __float_as_uint(f);
  u += 0x7FFFu + ((u >> 16) & 1u);   // round-to-nearest-even
  return (unsigned short)(u >> 16);
}

// ---------------- coherent (IF$) helpers: sc0 sc1 bypass L1+L2 ----------------
__device__ __forceinline__ void st_u32_coh(unsigned int* p, unsigned int v) {
  asm volatile("global_store_dword %0, %1, off sc0 sc1" ::"v"(p), "v"(v) : "memory");
}
__device__ __forceinline__ void st_u16_coh(unsigned short* p, unsigned int v) {
  asm volatile("global_store_short %0, %1, off sc0 sc1" ::"v"(p), "v"(v) : "memory");
}
__device__ __forceinline__ void st_u8_coh(unsigned char* p, unsigned int v) {
  asm volatile("global_store_byte %0, %1, off sc0 sc1" ::"v"(p), "v"(v) : "memory");
}

// coherent 16B load (bypass L1+L2) at literal byte offset
#define COH_LD16(dst, p, OFF)                                             \
  asm volatile("global_load_dwordx4 %0, %1, off offset:" #OFF " sc0 sc1"  \
               : "=v"(dst) : "v"(p) : "memory")
// cached 16B load (normal path) at literal byte offset — for read-only x
#define CA_LD16(dst, p, OFF)                                              \
  asm volatile("global_load_dwordx4 %0, %1, off offset:" #OFF              \
               : "=v"(dst) : "v"(p) : "memory")

__device__ __forceinline__ void wait_vm0(void) {
  asm volatile("s_waitcnt vmcnt(0)" ::: "memory");
  __builtin_amdgcn_sched_barrier(0);  // rule #18
}
__device__ __forceinline__ void wait_vm4(void) {
  // in-order completion: leaves the 4 newest (stage) loads in flight
  asm volatile("s_waitcnt vmcnt(4)" ::: "memory");
  __builtin_amdgcn_sched_barrier(0);
}

// wave-parallel poll of a 128B flag block: lanes 0..31 watch one dword each
__device__ __forceinline__ int wave_poll128(const unsigned char* p, int lane) {
  const unsigned int* pw = (const unsigned int*)p + (lane & 31);
  for (int i = 0; i < kSpinCap; ++i) {
    unsigned int v;
    asm volatile("global_load_dword %0, %1, off sc0 sc1\n\ts_waitcnt vmcnt(0)"
                 : "=v"(v) : "v"(pw) : "memory");
    if (__all((lane < 32) ? (int)(v == kDone4) : 1)) return 1;
  }
  return 0;
}

// ---------------- init: coherent zeros (flags) ----------------
__global__ void init_coh(unsigned int* __restrict__ zbase, int n) {
  int i = blockIdx.x * blockDim.x + threadIdx.x;
  if (i < n) st_u32_coh(zbase + i, 0u);
}

// ---------------- fp32 -> bf16 converts ----------------
__global__ void cvt_f32_bf16(const float* __restrict__ in,
                             unsigned short* __restrict__ out, int n4) {
  int i = blockIdx.x * blockDim.x + threadIdx.x;
  if (i >= n4) return;
  float4 v = ((const float4*)in)[i];
  ushort4 o;
  o.x = f2bf(v.x); o.y = f2bf(v.y); o.z = f2bf(v.z); o.w = f2bf(v.w);
  ((ushort4*)out)[i] = o;
}

// x [B][S][I] fp32 -> xbf [S][B][I] bf16 (time-major)
__global__ void cvt_x_t(const float* __restrict__ in,
                        unsigned short* __restrict__ out, int n4) {
  int i4 = blockIdx.x * blockDim.x + threadIdx.x;
  if (i4 >= n4) return;
  int d = i4 * 4;
  int i = d & (kH - 1);
  int rem = d / kH;
  int b = rem & (kB - 1);
  int s = rem / kB;
  float4 v = *(const float4*)(in + ((size_t)b * kS + s) * kH + i);
  ushort4 o;
  o.x = f2bf(v.x); o.y = f2bf(v.y); o.z = f2bf(v.z); o.w = f2bf(v.w);
  *(ushort4*)(out + (size_t)d) = o;
}

// ---------------- fused persistent 2-layer GRU (R11 + shuffle-gates) ----------------
// 256 WGs: layer (wgid>>7) x bg (wgid&3, 16 batches) x ug ((wgid&127)>>2,
// 16 units). LDS h-stage (16KB) shared by 4 waves; gates via in-wave __shfl
// (C cols {j,4+j,8+j} live in the same wave); per-wave publish + per-wave
// flag byte. Layer-0 x fragments register-prefetched across the poll.
__launch_bounds__(256, 1)
__global__ void gru_fused(const unsigned short* __restrict__ xbf,   // [S][B][H]
                          const unsigned short* __restrict__ wih0,  // [3H][H]
                          const unsigned short* __restrict__ whh0,
                          const unsigned short* __restrict__ wih1,
                          const unsigned short* __restrict__ whh1,
                          const float* __restrict__ bih0, const float* __restrict__ bhh0,
                          const float* __restrict__ bih1, const float* __restrict__ bhh1,
                          unsigned short* __restrict__ hs0,    // [S][B][H] bf16
                          unsigned short* __restrict__ h1buf,  // [2][B][H] bf16
                          unsigned char* __restrict__ f0,      // [S][4][32][4] wave flags
                          unsigned char* __restrict__ f1,
                          float* __restrict__ out) {
  const int tid  = threadIdx.x;
  const int lane = tid & 63;
  const int wv   = tid >> 6;                  // wave 0..3
  const int wgid = blockIdx.x;
  const int layer = wgid >> 7;
  const int bg    = wgid & 3;                 // batch group
  const int ug    = (wgid & 127) >> 2;        // unit group
  const int bgb0  = bg * 16;
  const int j0w   = ug * 16 + wv * 4;         // this wave's 4 units

  const unsigned short* wih = layer ? wih1 : wih0;
  const unsigned short* whh = layer ? whh1 : whh0;
  const float* bih = layer ? bih1 : bih0;
  const float* bhh = layer ? bhh1 : bhh0;

  // ---- B-fragments (12 gate rows of this wave's 4 units) in VGPRs ----
  // col n: gate = n>>2, unit = j0w + (n&3)  ->  unit j's gates at cols {j,4+j,8+j}
  bf16x8 bx[16], bh[16];
  {
    const int n = lane & 15, hi = lane >> 4;
    if (n < 12) {
      const int orig = (n >> 2) * kH + j0w + (n & 3);
      const unsigned short* pX = wih + (size_t)orig * kH + hi * 8;
      const unsigned short* pH = whh + (size_t)orig * kH + hi * 8;
#pragma unroll
      for (int kk = 0; kk < 16; ++kk) {
        bx[kk] = *(const bf16x8*)(pX + kk * 32);
        bh[kk] = *(const bf16x8*)(pH + kk * 32);
      }
    } else {
      bf16x8 z = {0, 0, 0, 0, 0, 0, 0, 0};
#pragma unroll
      for (int kk = 0; kk < 16; ++kk) { bx[kk] = z; bh[kk] = z; }
    }
  }

  const int n_   = lane & 15;     // C col (gate-row) / A batch row
  const int hi_  = lane >> 4;
  const int ahi  = hi_ * 8;       // A k sub-offset
  const int m0   = hi_ * 4;       // C batch base for this lane's 4 rows
  const int srow = n_;            // stage row
  const int scol0 = wv * 128 + hi_ * 32;  // stage col base
  const int jj    = lane & 3;     // unit-in-wave (valid when n_ < 4)
  const int src_z = (lane & 48) + jj + 4;
  const int src_n = (lane & 48) + jj + 8;
  const int u     = j0w + jj;     // this lane's unit (gate-math role)

  const float bihr = bih[u], bihz = bih[kH + u], bihn = bih[2 * kH + u];
  const float bhhr = bhh[u], bhhz = bhh[kH + u], bhhn = bhh[2 * kH + u];
  f32x4 hprev = {0.f, 0.f, 0.f, 0.f};

  __shared__ unsigned short hA[16][kHst];  // staged h_{t-1}[16 batches][512]
  __shared__ unsigned short hX[16][kHst];  // staged hs0[t] (layer 1)

  unsigned char* myf = layer ? f1 : f0;

  // ---- layer 0: prefetch x fragments for t=0 (held in regs across poll) ----
  bf16x8 axr[16];
  if (layer == 0) {
    const unsigned short* p = xbf + ((size_t)0 * kB + bgb0 + n_) * kH + ahi;
    CA_LD16(axr[0],  p, 0);   CA_LD16(axr[1],  p, 64);  CA_LD16(axr[2],  p, 128);
    CA_LD16(axr[3],  p, 192); CA_LD16(axr[4],  p, 256); CA_LD16(axr[5],  p, 320);
    CA_LD16(axr[6],  p, 384); CA_LD16(axr[7],  p, 448); CA_LD16(axr[8],  p, 512);
    CA_LD16(axr[9],  p, 576); CA_LD16(axr[10], p, 640); CA_LD16(axr[11], p, 704);
    CA_LD16(axr[12], p, 768); CA_LD16(axr[13], p, 832); CA_LD16(axr[14], p, 896);
    CA_LD16(axr[15], p, 960);
  }

  for (int t = 0; t < kS; ++t) {
    // ---- wait: wave-parallel poll (wave 0, and wave 1 for layer-1 chain) ----
    int ok = 1;
    if (layer == 0) {
      if (t > 0 && wv == 0)
        ok = wave_poll128(f0 + ((size_t)(t - 1) * kNBG + bg) * (kNUG * 4), lane);
    } else {
      if (wv == 0)
        ok = wave_poll128(f0 + ((size_t)t * kNBG + bg) * (kNUG * 4), lane);
      else if (t > 0 && wv == 1)
        ok = wave_poll128(f1 + ((size_t)(t - 1) * kNBG + bg) * (kNUG * 4), lane);
    }
    if (!__syncthreads_and(ok)) return;  // fail-fast bail

    // ---- stage issue (coherent; 64B/lane) ----
    bf16x8 tA[4], tX[4];
    if (t > 0) {
      const unsigned short* sp =
          (layer == 0) ? hs0 + ((size_t)(t - 1) * kB + bgb0 + srow) * kH + scol0
                       : h1buf + ((size_t)((t - 1) & 1) * kB + bgb0 + srow) * kH + scol0;
      COH_LD16(tA[0], sp, 0);  COH_LD16(tA[1], sp, 16);
      COH_LD16(tA[2], sp, 32); COH_LD16(tA[3], sp, 48);
    }
    if (layer == 1) {
      const unsigned short* sx = hs0 + ((size_t)t * kB + bgb0 + srow) * kH + scol0;
      COH_LD16(tX[0], sx, 0);  COH_LD16(tX[1], sx, 16);
      COH_LD16(tX[2], sx, 32); COH_LD16(tX[3], sx, 48);
    }

    f32x4 accx = {0.f, 0.f, 0.f, 0.f};
    f32x4 acch = {0.f, 0.f, 0.f, 0.f};

    if (layer == 0) {
      // gx GEMM from prefetched regs, overlapped with the stage round trip
      if (t > 0) wait_vm4(); else wait_vm0();  // prefetch done (in-order)
#pragma unroll
      for (int kk = 0; kk < 16; ++kk)
        accx = __builtin_amdgcn_mfma_f32_16x16x32_bf16(axr[kk], bx[kk], accx, 0, 0, 0);
      wait_vm0();  // stage loads done
      if (t > 0) {
#pragma unroll
        for (int it = 0; it < 4; ++it)
          *(bf16x8*)&hA[srow][scol0 + it * 8] = tA[it];
      }
      __syncthreads();
      if (t > 0) {
#pragma unroll
        for (int kk = 0; kk < 16; ++kk) {
          bf16x8 ahv = *(const bf16x8*)&hA[n_][kk * 32 + ahi];
          acch = __builtin_amdgcn_mfma_f32_16x16x32_bf16(ahv, bh[kk], acch, 0, 0, 0);
        }
      }
    } else {
      wait_vm0();
#pragma unroll
      for (int it = 0; it < 4; ++it)
        *(bf16x8*)&hX[srow][scol0 + it * 8] = tX[it];
      if (t > 0) {
#pragma unroll
        for (int it = 0; it < 4; ++it)
          *(bf16x8*)&hA[srow][scol0 + it * 8] = tA[it];
      }
      __syncthreads();
#pragma unroll
      for (int kk = 0; kk < 16; ++kk) {
        bf16x8 axv = *(const bf16x8*)&hX[n_][kk * 32 + ahi];
        accx = __builtin_amdgcn_mfma_f32_16x16x32_bf16(axv, bx[kk], accx, 0, 0, 0);
      }
      if (t > 0) {
#pragma unroll
        for (int kk = 0; kk < 16; ++kk) {
          bf16x8 ahv = *(const bf16x8*)&hA[n_][kk * 32 + ahi];
          acch = __builtin_amdgcn_mfma_f32_16x16x32_bf16(ahv, bh[kk], acch, 0, 0, 0);
        }
      }
    }

    // ---- in-wave gate gather: pull cols {4+j, 8+j} via shuffles ----
    f32x4 xz_, xn_, hz_, hn_;
#pragma unroll
    for (int r = 0; r < 4; ++r) {
      xz_[r] = __shfl(accx[r], src_z, 64);
      xn_[r] = __shfl(accx[r], src_n, 64);
      hz_[r] = __shfl(acch[r], src_z, 64);
      hn_[r] = __shfl(acch[r], src_n, 64);
    }
    f32x4 hnew;
#pragma unroll
    for (int r = 0; r < 4; ++r) {
      const float xr = accx[r] + bihr;
      const float xz = xz_[r] + bihz;
      const float xn = xn_[r] + bihn;
      const float hr = acch[r] + bhhr;
      const float hzv = hz_[r] + bhhz;
      const float hnv = hn_[r] + bhhn;
      const float rr = 1.0f / (1.0f + __expf(-(xr + hr)));
      const float zz = 1.0f / (1.0f + __expf(-(xz + hzv)));
      const float nn = tanhf(xn + rr * hnv);
      hnew[r] = (1.0f - zz) * nn + zz * hprev[r];
    }
    hprev = hnew;

    // ---- publish from registers (lanes with n_ < 4: unit u, batches m0..+3) ----
    if (n_ < 4) {
#pragma unroll
      for (int r = 0; r < 4; ++r) {
        const unsigned int hv = f2bf(hnew[r]);
        if (layer == 0) {
          st_u16_coh(hs0 + ((size_t)t * kB + bgb0 + m0 + r) * kH + u, hv);
        } else {
          st_u16_coh(h1buf + ((size_t)(t & 1) * kB + bgb0 + m0 + r) * kH + u, hv);
          out[((size_t)(bgb0 + m0 + r) * kS + t) * kH + u] = hnew[r];  // plain
        }
      }
      if (t == kS - 1) {
#pragma unroll
        for (int r = 0; r < 4; ++r)
          out[(size_t)kB * kS * kH + (size_t)layer * kB * kH +
              (size_t)(bgb0 + m0 + r) * kH + u] = hnew[r];
      }
    }
    // per-wave drain (IF$ ack of this wave's publishes), then wave flag byte
    asm volatile("s_waitcnt vmcnt(0)" ::: "memory");
    if (lane == 0)
      st_u8_coh(myf + ((size_t)t * kNBG + bg) * (kNUG * 4) + ug * 4 + wv, 1u);

    // ---- layer 0: prefetch next step's x fragments (completes during poll) ----
    if (layer == 0 && t + 1 < kS) {
      const unsigned short* p = xbf + ((size_t)(t + 1) * kB + bgb0 + n_) * kH + ahi;
      CA_LD16(axr[0],  p, 0);   CA_LD16(axr[1],  p, 64);  CA_LD16(axr[2],  p, 128);
      CA_LD16(axr[3],  p, 192); CA_LD16(axr[4],  p, 256); CA_LD16(axr[5],  p, 320);
      CA_LD16(axr[6],  p, 384); CA_LD16(axr[7],  p, 448); CA_LD16(axr[8],  p, 512);
      CA_LD16(axr[9],  p, 576); CA_LD16(axr[10], p, 640); CA_LD16(axr[11], p, 704);
      CA_LD16(axr[12], p, 768); CA_LD16(axr[13], p, 832); CA_LD16(axr[14], p, 896);
      CA_LD16(axr[15], p, 960);
    }
  }
}

extern "C" void kernel_launch(void* const* d_in, const int* in_sizes, int n_in,
                              void* d_out, int out_size, void* d_ws, size_t ws_size,
                              hipStream_t stream) {
  const float* x     = (const float*)d_in[0];
  const float* w_ih0 = (const float*)d_in[1];
  const float* w_hh0 = (const float*)d_in[2];
  const float* b_ih0 = (const float*)d_in[3];
  const float* b_hh0 = (const float*)d_in[4];
  const float* w_ih1 = (const float*)d_in[5];
  const float* w_hh1 = (const float*)d_in[6];
  const float* b_ih1 = (const float*)d_in[7];
  const float* b_hh1 = (const float*)d_in[8];
  float* out = (float*)d_out;

  // ---- workspace layout (ushort elems unless noted) ----
  unsigned short* ws = (unsigned short*)d_ws;
  const size_t nX = (size_t)kB * kS * kH;   // 33,554,432
  const size_t nW = (size_t)3 * kH * kH;    // 786,432
  unsigned short* xbf   = ws;
  unsigned short* wih0b = xbf + nX;
  unsigned short* whh0b = wih0b + nW;
  unsigned short* wih1b = whh0b + nW;
  unsigned short* whh1b = wih1b + nW;
  unsigned short* hs0   = whh1b + nW;             // nX elems
  unsigned short* h1buf = hs0 + nX;               // 2*B*H
  unsigned char*  f0    = (unsigned char*)(h1buf + 2 * kB * kH);  // S*4*32*4
  unsigned char*  f1    = f0 + (size_t)kS * kNBG * kNUG * 4;

  // zero both flag arrays (contiguous 1MB) coherently each launch
  {
    int nz = (int)(2 * (size_t)kS * kNBG * kNUG * 4 / 4);   // 262144 u32
    init_coh<<<(nz + 255) / 256, 256, 0, stream>>>((unsigned int*)f0, nz);
  }
  // converts
  {
    int n4 = (int)(nX / 4);
    cvt_x_t<<<n4 / 256, 256, 0, stream>>>(x, xbf, n4);
    int w4 = (int)(nW / 4);
    cvt_f32_bf16<<<w4 / 256, 256, 0, stream>>>(w_ih0, wih0b, w4);
    cvt_f32_bf16<<<w4 / 256, 256, 0, stream>>>(w_hh0, whh0b, w4);
    cvt_f32_bf16<<<w4 / 256, 256, 0, stream>>>(w_ih1, wih1b, w4);
    cvt_f32_bf16<<<w4 / 256, 256, 0, stream>>>(w_hh1, whh1b, w4);
  }

  // fused persistent GRU — 256 blocks (capacity >= grid, all co-resident)
  gru_fused<<<dim3(256), dim3(256), 0, stream>>>(
      xbf, wih0b, whh0b, wih1b, whh1b,
      b_ih0, b_hh0, b_ih1, b_hh1,
      hs0, h1buf, f0, f1, out);
}

// Round 14
// 6838.729 us; speedup vs baseline: 1.1325x; 1.1325x over previous
//
#include <hip/hip_runtime.h>
#include <hip/hip_bf16.h>
#include <cstddef>

typedef __attribute__((ext_vector_type(8))) short bf16x8;
typedef __attribute__((ext_vector_type(4))) float f32x4;
typedef __attribute__((ext_vector_type(4))) unsigned int u32x4;

constexpr int kB = 64;      // batch
constexpr int kS = 1024;    // seq len
constexpr int kH = 512;     // hidden (== input size)
constexpr int kNBG = 4;     // batch groups (16 batches each)
constexpr int kNUG = 32;    // unit groups (16 units each)
constexpr int kHst = 520;   // padded LDS h-stage row stride (elems)
constexpr unsigned kDone4 = 0x01010101u;
constexpr int kSpinCap = 1 << 16;  // fail-fast

__device__ __forceinline__ unsigned short f2bf(float f) {
  unsigned int u = __float_as_uint(f);
  u += 0x7FFFu + ((u >> 16) & 1u);   // round-to-nearest-even
  return (unsigned short)(u >> 16);
}

// ---------------- coherent (IF$) helpers: sc0 sc1 bypass L1+L2 ----------------
__device__ __forceinline__ void st_u32_coh(unsigned int* p, unsigned int v) {
  asm volatile("global_store_dword %0, %1, off sc0 sc1" ::"v"(p), "v"(v) : "memory");
}
__device__ __forceinline__ void st_u64_coh(void* p, unsigned long long v) {
  asm volatile("global_store_dwordx2 %0, %1, off sc0 sc1" ::"v"(p), "v"(v) : "memory");
}
__device__ __forceinline__ void st_u8_coh(unsigned char* p, unsigned int v) {
  asm volatile("global_store_byte %0, %1, off sc0 sc1" ::"v"(p), "v"(v) : "memory");
}

// coherent 16B load (bypass L1+L2) at literal byte offset
#define COH_LD16(dst, p, OFF)                                             \
  asm volatile("global_load_dwordx4 %0, %1, off offset:" #OFF " sc0 sc1"  \
               : "=v"(dst) : "v"(p) : "memory")
// cached 16B load (normal path) — read-only x
#define CA_LD16(dst, p, OFF)                                              \
  asm volatile("global_load_dwordx4 %0, %1, off offset:" #OFF              \
               : "=v"(dst) : "v"(p) : "memory")

__device__ __forceinline__ void wait_vm0(void) {
  asm volatile("s_waitcnt vmcnt(0)" ::: "memory");
  __builtin_amdgcn_sched_barrier(0);  // rule #18
}
__device__ __forceinline__ void wait_vm4(void) {
  asm volatile("s_waitcnt vmcnt(4)" ::: "memory");
  __builtin_amdgcn_sched_barrier(0);
}
__device__ __forceinline__ void wait_vm8(void) {
  asm volatile("s_waitcnt vmcnt(8)" ::: "memory");
  __builtin_amdgcn_sched_barrier(0);
}

// single-thread poll of 32 contiguous done-bytes (2 x dwordx4), capped
__device__ __forceinline__ int poll32(const unsigned char* p) {
  for (int i = 0; i < kSpinCap; ++i) {
    u32x4 a, b;
    asm volatile(
        "global_load_dwordx4 %0, %2, off sc0 sc1\n\t"
        "global_load_dwordx4 %1, %2, off offset:16 sc0 sc1\n\t"
        "s_waitcnt vmcnt(0)"
        : "=v"(a), "=v"(b) : "v"(p) : "memory");
    if (a[0] == kDone4 && a[1] == kDone4 && a[2] == kDone4 && a[3] == kDone4 &&
        b[0] == kDone4 && b[1] == kDone4 && b[2] == kDone4 && b[3] == kDone4)
      return 1;
  }
  return 0;
}

// ---------------- init: coherent zeros (flags) ----------------
__global__ void init_coh(unsigned int* __restrict__ zbase, int n) {
  int i = blockIdx.x * blockDim.x + threadIdx.x;
  if (i < n) st_u32_coh(zbase + i, 0u);
}

// ---------------- fp32 -> bf16 converts ----------------
__global__ void cvt_f32_bf16(const float* __restrict__ in,
                             unsigned short* __restrict__ out, int n4) {
  int i = blockIdx.x * blockDim.x + threadIdx.x;
  if (i >= n4) return;
  float4 v = ((const float4*)in)[i];
  ushort4 o;
  o.x = f2bf(v.x); o.y = f2bf(v.y); o.z = f2bf(v.z); o.w = f2bf(v.w);
  ((ushort4*)out)[i] = o;
}

// x [B][S][I] fp32 -> xbf [S][B][I] bf16 (time-major)
__global__ void cvt_x_t(const float* __restrict__ in,
                        unsigned short* __restrict__ out, int n4) {
  int i4 = blockIdx.x * blockDim.x + threadIdx.x;
  if (i4 >= n4) return;
  int d = i4 * 4;
  int i = d & (kH - 1);
  int rem = d / kH;
  int b = rem & (kB - 1);
  int s = rem / kB;
  float4 v = *(const float4*)(in + ((size_t)b * kS + s) * kH + i);
  ushort4 o;
  o.x = f2bf(v.x); o.y = f2bf(v.y); o.z = f2bf(v.z); o.w = f2bf(v.w);
  *(ushort4*)(out + (size_t)d) = o;
}

// ---------------- fused persistent 2-layer GRU, LAYER-MERGED epochs ----------------
// 128 WGs = bg (wgid&3, 16 batches) x ug (wgid>>2, 16 units). Epoch e:
// compute L0 step e AND L1 step e-1 in the same WG. One flag wait per epoch
// (flag[e-1] covers h0[e-1] and h1[e-2]); hA = h0[e-1] staged once, feeding
// BOTH L0's recurrent GEMM and L1's input GEMM. R11's proven protocol
// (sc0sc1 h + done-bytes + single poller + quad publishes) unchanged.
__launch_bounds__(256, 1)
__global__ void gru_fused(const unsigned short* __restrict__ xbf,   // [S][B][H]
                          const unsigned short* __restrict__ wih0,  // [3H][H]
                          const unsigned short* __restrict__ whh0,
                          const unsigned short* __restrict__ wih1,
                          const unsigned short* __restrict__ whh1,
                          const float* __restrict__ bih0, const float* __restrict__ bhh0,
                          const float* __restrict__ bih1, const float* __restrict__ bhh1,
                          unsigned short* __restrict__ hs0,    // [S][B][H] bf16
                          unsigned short* __restrict__ h1buf,  // [2][B][H] bf16
                          unsigned char* __restrict__ flags,   // [S][4][32] done-bytes
                          float* __restrict__ out) {
  const int tid  = threadIdx.x;
  const int lane = tid & 63;
  const int wv   = tid >> 6;                  // wave 0..3
  const int wgid = blockIdx.x;
  const int bg   = wgid & 3;                  // batch group
  const int ug   = wgid >> 2;                 // unit group 0..31
  const int bgb0 = bg * 16;
  const int j0w  = ug * 16 + wv * 4;          // this wave's 4 units

  // ---- B-fragments for BOTH layers (12 gate rows x 4 arrays) in VGPRs ----
  bf16x8 bx0[16], bh0f[16], bx1[16], bh1f[16];
  {
    const int n = lane & 15, hi = lane >> 4;
    if (n < 12) {
      const int orig = (n >> 2) * kH + j0w + (n & 3);  // gate*512 + unit
      const unsigned short* p0x = wih0 + (size_t)orig * kH + hi * 8;
      const unsigned short* p0h = whh0 + (size_t)orig * kH + hi * 8;
      const unsigned short* p1x = wih1 + (size_t)orig * kH + hi * 8;
      const unsigned short* p1h = whh1 + (size_t)orig * kH + hi * 8;
#pragma unroll
      for (int kk = 0; kk < 16; ++kk) {
        bx0[kk]  = *(const bf16x8*)(p0x + kk * 32);
        bh0f[kk] = *(const bf16x8*)(p0h + kk * 32);
        bx1[kk]  = *(const bf16x8*)(p1x + kk * 32);
        bh1f[kk] = *(const bf16x8*)(p1h + kk * 32);
      }
    } else {
      bf16x8 z = {0, 0, 0, 0, 0, 0, 0, 0};
#pragma unroll
      for (int kk = 0; kk < 16; ++kk) { bx0[kk] = z; bh0f[kk] = z; bx1[kk] = z; bh1f[kk] = z; }
    }
  }

  // gate thread mapping: thread -> (batch gb in group, unit guu 0..15)
  const int gb  = tid & 15;
  const int guu = tid >> 4;
  const int unit = ug * 16 + guu;
  const float b0r = bih0[unit], b0z = bih0[kH + unit], b0n = bih0[2 * kH + unit];
  const float h0r = bhh0[unit], h0z = bhh0[kH + unit], h0n = bhh0[2 * kH + unit];
  const float b1r = bih1[unit], b1z = bih1[kH + unit], b1n = bih1[2 * kH + unit];
  const float h1r = bhh1[unit], h1z = bhh1[kH + unit], h1n = bhh1[2 * kH + unit];
  float hprev0 = 0.0f, hprev1 = 0.0f;

  __shared__ unsigned short hA[16][kHst];  // h0[e-1]: L0-gh AND L1-gx operand
  __shared__ unsigned short hB[16][kHst];  // h1[e-2]: L1-gh operand
  __shared__ float gx0l[16][52], gh0l[16][52];
  __shared__ float gx1l[16][52], gh1l[16][52];
  __shared__ unsigned short hl0[16][20], hl1[16][20];
  __shared__ float hlf[16][20];

  const int n_  = lane & 15;              // C col / A batch row
  const int hi_ = lane >> 4;
  const int ahi = hi_ * 8;                // A k sub-offset
  const int srow = n_;                    // stage row
  const int scol0 = wv * 128 + hi_ * 32;  // stage col base

  // ---- prefetch x fragments for epoch 0 ----
  bf16x8 axr[16];
  {
    const unsigned short* p = xbf + ((size_t)0 * kB + bgb0 + n_) * kH + ahi;
    CA_LD16(axr[0],  p, 0);   CA_LD16(axr[1],  p, 64);  CA_LD16(axr[2],  p, 128);
    CA_LD16(axr[3],  p, 192); CA_LD16(axr[4],  p, 256); CA_LD16(axr[5],  p, 320);
    CA_LD16(axr[6],  p, 384); CA_LD16(axr[7],  p, 448); CA_LD16(axr[8],  p, 512);
    CA_LD16(axr[9],  p, 576); CA_LD16(axr[10], p, 640); CA_LD16(axr[11], p, 704);
    CA_LD16(axr[12], p, 768); CA_LD16(axr[13], p, 832); CA_LD16(axr[14], p, 896);
    CA_LD16(axr[15], p, 960);
  }

  for (int e = 0; e <= kS; ++e) {
    // ---- one flag wait per epoch: flag[e-1] gates h0[e-1] AND h1[e-2] ----
    int ok = 1;
    if (e >= 1 && tid == 0)
      ok = poll32(flags + ((size_t)(e - 1) * kNBG + bg) * kNUG);
    if (!__syncthreads_and(ok)) return;  // fail-fast bail

    // ---- stage issues (coherent) ----
    bf16x8 tA[4], tB[4];
    if (e >= 1) {
      const unsigned short* sp = hs0 + ((size_t)(e - 1) * kB + bgb0 + srow) * kH + scol0;
      COH_LD16(tA[0], sp, 0);  COH_LD16(tA[1], sp, 16);
      COH_LD16(tA[2], sp, 32); COH_LD16(tA[3], sp, 48);
    }
    if (e >= 2) {
      const unsigned short* sb = h1buf + ((size_t)((e - 2) & 1) * kB + bgb0 + srow) * kH + scol0;
      COH_LD16(tB[0], sb, 0);  COH_LD16(tB[1], sb, 16);
      COH_LD16(tB[2], sb, 32); COH_LD16(tB[3], sb, 48);
    }

    // ---- L0 input GEMM from prefetched regs (overlaps stage round trip) ----
    f32x4 ax0 = {0,0,0,0}, ah0 = {0,0,0,0}, ax1 = {0,0,0,0}, ah1 = {0,0,0,0};
    if (e < kS) {
      if (e >= 2) wait_vm8(); else if (e == 1) wait_vm4(); else wait_vm0();
#pragma unroll
      for (int kk = 0; kk < 16; ++kk)
        ax0 = __builtin_amdgcn_mfma_f32_16x16x32_bf16(axr[kk], bx0[kk], ax0, 0, 0, 0);
    }

    // ---- stage writes to LDS ----
    if (e >= 1) {
      wait_vm0();
#pragma unroll
      for (int it = 0; it < 4; ++it)
        *(bf16x8*)&hA[srow][scol0 + it * 8] = tA[it];
      if (e >= 2) {
#pragma unroll
        for (int it = 0; it < 4; ++it)
          *(bf16x8*)&hB[srow][scol0 + it * 8] = tB[it];
      }
    }
    __syncthreads();

    // ---- recurrent GEMMs (hA feeds both gh0 and gx1) ----
    if (e >= 1) {
#pragma unroll
      for (int kk = 0; kk < 16; ++kk) {
        bf16x8 av = *(const bf16x8*)&hA[n_][kk * 32 + ahi];
        if (e < kS)
          ah0 = __builtin_amdgcn_mfma_f32_16x16x32_bf16(av, bh0f[kk], ah0, 0, 0, 0);
        ax1 = __builtin_amdgcn_mfma_f32_16x16x32_bf16(av, bx1[kk], ax1, 0, 0, 0);
      }
      if (e >= 2) {
#pragma unroll
        for (int kk = 0; kk < 16; ++kk) {
          bf16x8 bv = *(const bf16x8*)&hB[n_][kk * 32 + ahi];
          ah1 = __builtin_amdgcn_mfma_f32_16x16x32_bf16(bv, bh1f[kk], ah1, 0, 0, 0);
        }
      }
    }
    // exchange writes: C row m=hi_*4+r (batch), col wv*12 + n_ (gate-row)
    if (n_ < 12) {
      const int m0 = hi_ * 4;
#pragma unroll
      for (int r = 0; r < 4; ++r) {
        gx0l[m0 + r][wv * 12 + n_] = ax0[r];
        gh0l[m0 + r][wv * 12 + n_] = ah0[r];
        gx1l[m0 + r][wv * 12 + n_] = ax1[r];
        gh1l[m0 + r][wv * 12 + n_] = ah1[r];
      }
    }
    __syncthreads();

    // ---- gates (both layers per thread) ----
    {
      const int c0 = (guu >> 2) * 12, du = guu & 3;
      if (e < kS) {  // L0 step t0 = e
        const float xr = gx0l[gb][c0 + du]     + b0r;
        const float xz = gx0l[gb][c0 + 4 + du] + b0z;
        const float xn = gx0l[gb][c0 + 8 + du] + b0n;
        const float hr = gh0l[gb][c0 + du]     + h0r;
        const float hz = gh0l[gb][c0 + 4 + du] + h0z;
        const float hn = gh0l[gb][c0 + 8 + du] + h0n;
        const float r = 1.0f / (1.0f + __expf(-(xr + hr)));
        const float z = 1.0f / (1.0f + __expf(-(xz + hz)));
        const float nv = tanhf(xn + r * hn);
        const float hnew = (1.0f - z) * nv + z * hprev0;
        hprev0 = hnew;
        hl0[gb][guu] = f2bf(hnew);
        if (e == kS - 1)
          out[(size_t)kB * kS * kH + (size_t)(bgb0 + gb) * kH + unit] = hnew;
      }
      if (e >= 1) {  // L1 step t1 = e-1
        const float xr = gx1l[gb][c0 + du]     + b1r;
        const float xz = gx1l[gb][c0 + 4 + du] + b1z;
        const float xn = gx1l[gb][c0 + 8 + du] + b1n;
        const float hr = gh1l[gb][c0 + du]     + h1r;
        const float hz = gh1l[gb][c0 + 4 + du] + h1z;
        const float hn = gh1l[gb][c0 + 8 + du] + h1n;
        const float r = 1.0f / (1.0f + __expf(-(xr + hr)));
        const float z = 1.0f / (1.0f + __expf(-(xz + hz)));
        const float nv = tanhf(xn + r * hn);
        const float hnew = (1.0f - z) * nv + z * hprev1;
        hprev1 = hnew;
        hl1[gb][guu] = f2bf(hnew);
        hlf[gb][guu] = hnew;
        if (e == kS)
          out[(size_t)kB * kS * kH + (size_t)kB * kH + (size_t)(bgb0 + gb) * kH + unit] = hnew;
      }
    }
    __syncthreads();

    // ---- publish: wave 0 -> h0 + h1 (coherent quads); wave 1 -> out fp32 ----
    if (tid < 64) {
      const int b = tid >> 2, q = tid & 3;
      if (e < kS)
        st_u64_coh(hs0 + ((size_t)e * kB + bgb0 + b) * kH + ug * 16 + q * 4,
                   *(const unsigned long long*)&hl0[b][q * 4]);
      if (e >= 1)
        st_u64_coh(h1buf + ((size_t)((e - 1) & 1) * kB + bgb0 + b) * kH + ug * 16 + q * 4,
                   *(const unsigned long long*)&hl1[b][q * 4]);
    } else if (tid < 128 && e >= 1) {
      const int b = (tid - 64) >> 2, q = (tid - 64) & 3;
      *(float4*)(out + ((size_t)(bgb0 + b) * kS + (e - 1)) * kH + ug * 16 + q * 4) =
          *(const float4*)&hlf[b][q * 4];  // [b][t][h], plain (kernel-end flush)
    }
    if (tid == 0 && e < kS) {
      asm volatile("s_waitcnt vmcnt(0)" ::: "memory");  // wave-0 publish drain
      st_u8_coh(flags + ((size_t)e * kNBG + bg) * kNUG + ug, 1u);
    }

    // ---- prefetch next epoch's x fragments (complete during next poll) ----
    if (e + 1 < kS) {
      const unsigned short* p = xbf + ((size_t)(e + 1) * kB + bgb0 + n_) * kH + ahi;
      CA_LD16(axr[0],  p, 0);   CA_LD16(axr[1],  p, 64);  CA_LD16(axr[2],  p, 128);
      CA_LD16(axr[3],  p, 192); CA_LD16(axr[4],  p, 256); CA_LD16(axr[5],  p, 320);
      CA_LD16(axr[6],  p, 384); CA_LD16(axr[7],  p, 448); CA_LD16(axr[8],  p, 512);
      CA_LD16(axr[9],  p, 576); CA_LD16(axr[10], p, 640); CA_LD16(axr[11], p, 704);
      CA_LD16(axr[12], p, 768); CA_LD16(axr[13], p, 832); CA_LD16(axr[14], p, 896);
      CA_LD16(axr[15], p, 960);
    }
  }
}

extern "C" void kernel_launch(void* const* d_in, const int* in_sizes, int n_in,
                              void* d_out, int out_size, void* d_ws, size_t ws_size,
                              hipStream_t stream) {
  const float* x     = (const float*)d_in[0];
  const float* w_ih0 = (const float*)d_in[1];
  const float* w_hh0 = (const float*)d_in[2];
  const float* b_ih0 = (const float*)d_in[3];
  const float* b_hh0 = (const float*)d_in[4];
  const float* w_ih1 = (const float*)d_in[5];
  const float* w_hh1 = (const float*)d_in[6];
  const float* b_ih1 = (const float*)d_in[7];
  const float* b_hh1 = (const float*)d_in[8];
  float* out = (float*)d_out;

  // ---- workspace layout (ushort elems unless noted) ----
  unsigned short* ws = (unsigned short*)d_ws;
  const size_t nX = (size_t)kB * kS * kH;   // 33,554,432
  const size_t nW = (size_t)3 * kH * kH;    // 786,432
  unsigned short* xbf   = ws;
  unsigned short* wih0b = xbf + nX;
  unsigned short* whh0b = wih0b + nW;
  unsigned short* wih1b = whh0b + nW;
  unsigned short* whh1b = wih1b + nW;
  unsigned short* hs0   = whh1b + nW;             // nX elems
  unsigned short* h1buf = hs0 + nX;               // 2*B*H
  unsigned char*  flags = (unsigned char*)(h1buf + 2 * kB * kH);  // S*4*32

  // zero flags (128KB) coherently each launch
  {
    int nz = (int)((size_t)kS * kNBG * kNUG / 4);   // 32768 u32
    init_coh<<<(nz + 255) / 256, 256, 0, stream>>>((unsigned int*)flags, nz);
  }
  // converts
  {
    int n4 = (int)(nX / 4);
    cvt_x_t<<<n4 / 256, 256, 0, stream>>>(x, xbf, n4);
    int w4 = (int)(nW / 4);
    cvt_f32_bf16<<<w4 / 256, 256, 0, stream>>>(w_ih0, wih0b, w4);
    cvt_f32_bf16<<<w4 / 256, 256, 0, stream>>>(w_hh0, whh0b, w4);
    cvt_f32_bf16<<<w4 / 256, 256, 0, stream>>>(w_ih1, wih1b, w4);
    cvt_f32_bf16<<<w4 / 256, 256, 0, stream>>>(w_hh1, whh1b, w4);
  }

  // fused persistent GRU — 128 blocks (both layers per WG), all co-resident
  gru_fused<<<dim3(kNBG * kNUG), dim3(256), 0, stream>>>(
      xbf, wih0b, whh0b, wih1b, whh1b,
      b_ih0, b_hh0, b_ih1, b_hh1,
      hs0, h1buf, flags, out);
}

// Round 18
// 5304.318 us; speedup vs baseline: 1.4601x; 1.2893x over previous
//
#include <hip/hip_runtime.h>
#include <hip/hip_bf16.h>
#include <cstddef>

typedef __attribute__((ext_vector_type(8))) short bf16x8;
typedef __attribute__((ext_vector_type(4))) float f32x4;
typedef __attribute__((ext_vector_type(4))) unsigned int u32x4;

constexpr int kB = 64;      // batch
constexpr int kS = 1024;    // seq len
constexpr int kH = 512;     // hidden (== input size)
constexpr int kNBG = 4;     // batch groups (16 batches each)
constexpr int kNUG = 32;    // unit groups per layer (16 units each)
constexpr int kHst = 520;   // padded LDS h-stage row stride (elems)
constexpr unsigned kDone4 = 0x01010101u;
constexpr int kSpinCap = 1 << 16;  // fail-fast

__device__ __forceinline__ unsigned short f2bf(float f) {
  unsigned int u = __float_as_uint(f);
  u += 0x7FFFu + ((u >> 16) & 1u);   // round-to-nearest-even
  return (unsigned short)(u >> 16);
}

// ---------------- coherent (IF$-level) helpers: sc0 sc1 bypass L1+L2 ----------------
__device__ __forceinline__ void st_u32_coh(unsigned int* p, unsigned int v) {
  asm volatile("global_store_dword %0, %1, off sc0 sc1" ::"v"(p), "v"(v) : "memory");
}
__device__ __forceinline__ void st_u64_coh(void* p, unsigned long long v) {
  asm volatile("global_store_dwordx2 %0, %1, off sc0 sc1" ::"v"(p), "v"(v) : "memory");
}
// drain wave's outstanding stores (IF$ ack), then set done-byte
__device__ __forceinline__ void st_flag_release8(unsigned char* p, unsigned int v) {
  asm volatile("s_waitcnt vmcnt(0)\n\tglobal_store_byte %0, %1, off sc0 sc1"
               ::"v"(p), "v"(v) : "memory");
}

#define COH_LD16(dst, p, OFF)                                             \
  asm volatile("global_load_dwordx4 %0, %1, off offset:" #OFF " sc0 sc1"  \
               : "=v"(dst) : "v"(p) : "memory")

__device__ __forceinline__ void wait_vm0(void) {
  asm volatile("s_waitcnt vmcnt(0)" ::: "memory");
  __builtin_amdgcn_sched_barrier(0);  // rule #18
}

// single-thread poll of 32 contiguous done-bytes (2 x dwordx4), capped
__device__ __forceinline__ int poll32(const unsigned char* p) {
  for (int i = 0; i < kSpinCap; ++i) {
    u32x4 a, b;
    asm volatile(
        "global_load_dwordx4 %0, %2, off sc0 sc1\n\t"
        "global_load_dwordx4 %1, %2, off offset:16 sc0 sc1\n\t"
        "s_waitcnt vmcnt(0)"
        : "=v"(a), "=v"(b) : "v"(p) : "memory");
    if (a[0] == kDone4 && a[1] == kDone4 && a[2] == kDone4 && a[3] == kDone4 &&
        b[0] == kDone4 && b[1] == kDone4 && b[2] == kDone4 && b[3] == kDone4)
      return 1;
  }
  return 0;
}

// ---------------- init: coherent zeros (flags) ----------------
__global__ void init_coh(unsigned int* __restrict__ zbase, int n) {
  int i = blockIdx.x * blockDim.x + threadIdx.x;
  if (i < n) st_u32_coh(zbase + i, 0u);
}

// ---------------- fp32 -> bf16 converts ----------------
__global__ void cvt_f32_bf16(const float* __restrict__ in,
                             unsigned short* __restrict__ out, int n4) {
  int i = blockIdx.x * blockDim.x + threadIdx.x;
  if (i >= n4) return;
  float4 v = ((const float4*)in)[i];
  ushort4 o;
  o.x = f2bf(v.x); o.y = f2bf(v.y); o.z = f2bf(v.z); o.w = f2bf(v.w);
  ((ushort4*)out)[i] = o;
}

// x [B][S][I] fp32 -> xbf [S][B][I] bf16 (time-major)
__global__ void cvt_x_t(const float* __restrict__ in,
                        unsigned short* __restrict__ out, int n4) {
  int i4 = blockIdx.x * blockDim.x + threadIdx.x;
  if (i4 >= n4) return;
  int d = i4 * 4;
  int i = d & (kH - 1);
  int rem = d / kH;
  int b = rem & (kB - 1);
  int s = rem / kB;
  float4 v = *(const float4*)(in + ((size_t)b * kS + s) * kH + i);
  ushort4 o;
  o.x = f2bf(v.x); o.y = f2bf(v.y); o.z = f2bf(v.z); o.w = f2bf(v.w);
  *(ushort4*)(out + (size_t)d) = o;
}

// ---------------- fused persistent 2-layer GRU, batch-group partition ----------------
// 256 WGs: layer = wgid>>7; bg = wgid&3 (16 batches); ug = (wgid&127)>>2
// (16 units). Recurrence is elementwise in batch -> each WG only ever needs
// h[its 16 batches][all 512], staged ONCE into LDS and shared by 4 waves
// (4x less IF$ traffic than units-only split). Waves split over N: wave wv
// owns units ug*16+wv*4..+3 (12 gate rows as VGPR B-frags, R7 shape).
// Sync: 32 done-bytes per (layer,bg,t), single-poller, fail-fast capped.
__launch_bounds__(256, 1)
__global__ void gru_fused(const unsigned short* __restrict__ xbf,   // [S][B][H]
                          const unsigned short* __restrict__ wih0,  // [3H][H]
                          const unsigned short* __restrict__ whh0,
                          const unsigned short* __restrict__ wih1,
                          const unsigned short* __restrict__ whh1,
                          const float* __restrict__ bih0, const float* __restrict__ bhh0,
                          const float* __restrict__ bih1, const float* __restrict__ bhh1,
                          unsigned short* __restrict__ hs0,    // [S][B][H] bf16
                          unsigned short* __restrict__ h1buf,  // [2][B][H] bf16
                          unsigned char* __restrict__ f0,      // [S][4][32] done-bytes
                          unsigned char* __restrict__ f1,
                          float* __restrict__ out) {
  const int tid  = threadIdx.x;
  const int lane = tid & 63;
  const int wv   = tid >> 6;                  // wave 0..3
  const int wgid = blockIdx.x;
  const int layer = wgid >> 7;
  const int bg    = wgid & 3;                 // batch group
  const int ug    = (wgid & 127) >> 2;        // unit group
  const int bgb0  = bg * 16;
  const int j0w   = ug * 16 + wv * 4;         // this wave's 4 units

  const unsigned short* wih = layer ? wih1 : wih0;
  const unsigned short* whh = layer ? whh1 : whh0;
  const float* bih = layer ? bih1 : bih0;
  const float* bhh = layer ? bhh1 : bhh0;

  // ---- B-fragments (12 gate rows of this wave's 4 units) in VGPRs ----
  bf16x8 bx[16], bh[16];
  {
    const int n = lane & 15, hi = lane >> 4;
    if (n < 12) {
      const int orig = (n >> 2) * kH + j0w + (n & 3);  // gate*512 + unit
      const unsigned short* pX = wih + (size_t)orig * kH + hi * 8;
      const unsigned short* pH = whh + (size_t)orig * kH + hi * 8;
#pragma unroll
      for (int kk = 0; kk < 16; ++kk) {
        bx[kk] = *(const bf16x8*)(pX + kk * 32);
        bh[kk] = *(const bf16x8*)(pH + kk * 32);
      }
    } else {
      bf16x8 z = {0, 0, 0, 0, 0, 0, 0, 0};
#pragma unroll
      for (int kk = 0; kk < 16; ++kk) { bx[kk] = z; bh[kk] = z; }
    }
  }

  // gate thread mapping: thread -> (batch gb in group, unit guu 0..15)
  const int gb  = tid & 15;
  const int guu = tid >> 4;
  const int unit = ug * 16 + guu;
  const float bihr = bih[unit], bihz = bih[kH + unit], bihn = bih[2 * kH + unit];
  const float bhhr = bhh[unit], bhhz = bhh[kH + unit], bhhn = bhh[2 * kH + unit];
  float hprev = 0.0f;

  __shared__ unsigned short hA[16][kHst];  // staged h_{t-1}[16 batches][512]
  __shared__ unsigned short hX[16][kHst];  // staged hs0[t] (layer 1 only)
  __shared__ float gxl[16][52];            // exchange: 4 waves x 12 cols
  __shared__ float ghl[16][52];
  __shared__ unsigned short hl[16][20];    // padded gather for publish
  __shared__ float hlf[16][20];

  // A-fragment lane coords (M = 16 batches of this group)
  const int n_  = lane & 15;
  const int ahi = (lane >> 4) * 8;
  // stage lane coords: lane -> (row, 32-col segment)
  const int srow  = lane & 15;
  const int scol0 = wv * 128 + (lane >> 4) * 32;

  unsigned char* myf = (layer ? f1 : f0);

  for (int t = 0; t < kS; ++t) {
    // ---- layer 0: input GEMM pre-poll (x L2/L1-cached, dependency-free) ----
    f32x4 accx = {0.f, 0.f, 0.f, 0.f};
    if (layer == 0) {
      const unsigned short* pAX = xbf + ((size_t)t * kB + bgb0 + n_) * kH + ahi;
#pragma unroll
      for (int kk = 0; kk < 16; ++kk) {
        bf16x8 ax = *(const bf16x8*)(pAX + kk * 32);
        accx = __builtin_amdgcn_mfma_f32_16x16x32_bf16(ax, bx[kk], accx, 0, 0, 0);
      }
    }

    // ---- wait: single poller per dependency (32 bytes each) ----
    int ok = 1;
    if (layer == 0) {
      if (t > 0 && tid == 0) ok = poll32(f0 + ((size_t)(t - 1) * kNBG + bg) * kNUG);
    } else {
      if (tid == 0) ok = poll32(f0 + ((size_t)t * kNBG + bg) * kNUG);
      else if (t > 0 && tid == 64) ok = poll32(f1 + ((size_t)(t - 1) * kNBG + bg) * kNUG);
    }
    if (!__syncthreads_and(ok)) return;  // fail-fast bail

    // ---- stage h into LDS (16 KB once per WG, shared by 4 waves) ----
    bf16x8 tA[4], tX[4];
    if (t > 0) {
      const unsigned short* sp =
          ((layer == 0) ? hs0 + ((size_t)(t - 1) * kB + bgb0 + srow) * kH
                        : h1buf + ((size_t)((t - 1) & 1) * kB + bgb0 + srow) * kH) + scol0;
      COH_LD16(tA[0], sp, 0); COH_LD16(tA[1], sp, 16);
      COH_LD16(tA[2], sp, 32); COH_LD16(tA[3], sp, 48);
    }
    if (layer == 1) {
      const unsigned short* sx =
          hs0 + ((size_t)t * kB + bgb0 + srow) * kH + scol0;
      COH_LD16(tX[0], sx, 0); COH_LD16(tX[1], sx, 16);
      COH_LD16(tX[2], sx, 32); COH_LD16(tX[3], sx, 48);
    }
    wait_vm0();
    if (t > 0) {
#pragma unroll
      for (int it = 0; it < 4; ++it)
        *(bf16x8*)&hA[srow][scol0 + it * 8] = tA[it];
    }
    if (layer == 1) {
#pragma unroll
      for (int it = 0; it < 4; ++it)
        *(bf16x8*)&hX[srow][scol0 + it * 8] = tX[it];
    }
    __syncthreads();

    // ---- GEMMs from LDS stage ----
    if (layer == 1) {
#pragma unroll
      for (int kk = 0; kk < 16; ++kk) {
        bf16x8 axv = *(const bf16x8*)&hX[n_][kk * 32 + ahi];
        accx = __builtin_amdgcn_mfma_f32_16x16x32_bf16(axv, bx[kk], accx, 0, 0, 0);
      }
    }
    f32x4 acch = {0.f, 0.f, 0.f, 0.f};
    if (t > 0) {
#pragma unroll
      for (int kk = 0; kk < 16; ++kk) {
        bf16x8 ahv = *(const bf16x8*)&hA[n_][kk * 32 + ahi];
        acch = __builtin_amdgcn_mfma_f32_16x16x32_bf16(ahv, bh[kk], acch, 0, 0, 0);
      }
    }
    // exchange write: C row m=(lane>>4)*4+r (batch), col wv*12 + n (gate-row)
    if (n_ < 12) {
      const int m0 = (lane >> 4) * 4;
#pragma unroll
      for (int r = 0; r < 4; ++r) {
        gxl[m0 + r][wv * 12 + n_] = accx[r];
        ghl[m0 + r][wv * 12 + n_] = acch[r];
      }
    }
    __syncthreads();

    // ---- gates: thread (gb, guu); source wave uw = guu>>2, du = guu&3 ----
    {
      const int c0 = (guu >> 2) * 12, du = guu & 3;
      const float xr = gxl[gb][c0 + du]     + bihr;
      const float xz = gxl[gb][c0 + 4 + du] + bihz;
      const float xn = gxl[gb][c0 + 8 + du] + bihn;
      const float hr = ghl[gb][c0 + du]     + bhhr;
      const float hzv = ghl[gb][c0 + 4 + du] + bhhz;
      const float hn = ghl[gb][c0 + 8 + du] + bhhn;
      const float r = 1.0f / (1.0f + __expf(-(xr + hr)));
      const float z = 1.0f / (1.0f + __expf(-(xz + hzv)));
      const float nn = tanhf(xn + r * hn);
      const float hnew = (1.0f - z) * nn + z * hprev;
      hprev = hnew;
      hl[gb][guu] = f2bf(hnew);
      if (layer == 1) hlf[gb][guu] = hnew;
      if (t == kS - 1)  // h_n epilogue (plain store, flushed at kernel end)
        out[(size_t)kB * kS * kH + (size_t)layer * kB * kH +
            (size_t)(bgb0 + gb) * kH + unit] = hnew;
    }
    __syncthreads();

    // ---- publish: wave 0 -> h (coherent); wave 1 -> out fp32 (plain) ----
    if (tid < 64) {
      const int b = tid >> 2, q = tid & 3;
      unsigned long long pk = *(const unsigned long long*)&hl[b][q * 4];
      if (layer == 0)
        st_u64_coh(hs0 + ((size_t)t * kB + bgb0 + b) * kH + ug * 16 + q * 4, pk);
      else
        st_u64_coh(h1buf + ((size_t)(t & 1) * kB + bgb0 + b) * kH + ug * 16 + q * 4, pk);
    } else if (tid < 128 && layer == 1) {
      const int b = (tid - 64) >> 2, q = (tid - 64) & 3;
      *(float4*)(out + ((size_t)(bgb0 + b) * kS + t) * kH + ug * 16 + q * 4) =
          *(const float4*)&hlf[b][q * 4];  // [b][t][h]
    }
    if (tid == 0)
      st_flag_release8(myf + ((size_t)t * kNBG + bg) * kNUG + ug, 1u);
    // no trailing barrier: next-iteration LDS writes are behind the next
    // poll/stage barriers, which wave 0 joins only after publish+flag.
  }
}

extern "C" void kernel_launch(void* const* d_in, const int* in_sizes, int n_in,
                              void* d_out, int out_size, void* d_ws, size_t ws_size,
                              hipStream_t stream) {
  const float* x     = (const float*)d_in[0];
  const float* w_ih0 = (const float*)d_in[1];
  const float* w_hh0 = (const float*)d_in[2];
  const float* b_ih0 = (const float*)d_in[3];
  const float* b_hh0 = (const float*)d_in[4];
  const float* w_ih1 = (const float*)d_in[5];
  const float* w_hh1 = (const float*)d_in[6];
  const float* b_ih1 = (const float*)d_in[7];
  const float* b_hh1 = (const float*)d_in[8];
  float* out = (float*)d_out;

  // ---- workspace layout (ushort elems unless noted) ----
  unsigned short* ws = (unsigned short*)d_ws;
  const size_t nX = (size_t)kB * kS * kH;   // 33,554,432
  const size_t nW = (size_t)3 * kH * kH;    // 786,432
  unsigned short* xbf   = ws;
  unsigned short* wih0b = xbf + nX;
  unsigned short* whh0b = wih0b + nW;
  unsigned short* wih1b = whh0b + nW;
  unsigned short* whh1b = wih1b + nW;
  unsigned short* hs0   = whh1b + nW;             // nX elems
  unsigned short* h1buf = hs0 + nX;               // 2*B*H
  unsigned char*  f0    = (unsigned char*)(h1buf + 2 * kB * kH);  // S*4*32
  unsigned char*  f1    = f0 + (size_t)kS * kNBG * kNUG;

  // zero both flag arrays (contiguous 256KB) coherently each launch
  {
    int nz = (int)(2 * (size_t)kS * kNBG * kNUG / 4);   // 65536 u32
    init_coh<<<(nz + 255) / 256, 256, 0, stream>>>((unsigned int*)f0, nz);
  }
  // converts
  {
    int n4 = (int)(nX / 4);
    cvt_x_t<<<n4 / 256, 256, 0, stream>>>(x, xbf, n4);
    int w4 = (int)(nW / 4);
    cvt_f32_bf16<<<w4 / 256, 256, 0, stream>>>(w_ih0, wih0b, w4);
    cvt_f32_bf16<<<w4 / 256, 256, 0, stream>>>(w_hh0, whh0b, w4);
    cvt_f32_bf16<<<w4 / 256, 256, 0, stream>>>(w_ih1, wih1b, w4);
    cvt_f32_bf16<<<w4 / 256, 256, 0, stream>>>(w_hh1, whh1b, w4);
  }

  // fused persistent GRU — 256 blocks (capacity >= grid, all co-resident)
  gru_fused<<<dim3(256), dim3(256), 0, stream>>>(
      xbf, wih0b, whh0b, wih1b, whh1b,
      b_ih0, b_hh0, b_ih1, b_hh1,
      hs0, h1buf, f0, f1, out);
}